// Round 7
// baseline (683684.033 us; speedup 1.0000x reference)
//
#include <hip/hip_runtime.h>

// ---------------------------------------------------------------------------
// RNN (LSTM) + CRF loss on MI355X — round 7.
// LSTM: XCD-replicated persistent kernel. Each of the 8 XCDs computes the FULL
// h recurrence redundantly; the per-step h exchange stays inside the XCD's
// shared L2 (sc0 loads/stores, ~200cy hops instead of ~900cy LLC hops).
// 256 blocks x 256 thr, 88KB LDS -> 1 block/CU -> exactly 32 blocks/XCD.
// Block slot via HW_REG_XCC_ID + per-XCD atomic. 4 waves = 2 batch-halves x
// 2 K-halves (no redundant h reads; partials merged via LDS). Weights
// register-resident (192 VGPR). Poll has bailout (no 600s-timeout mode).
// ---------------------------------------------------------------------------

typedef float f32x4 __attribute__((ext_vector_type(4)));
typedef float f32x16 __attribute__((ext_vector_type(16)));
typedef __bf16 bf16x8 __attribute__((ext_vector_type(8)));
typedef unsigned int u32x4 __attribute__((ext_vector_type(4)));
typedef unsigned int u32x2 __attribute__((ext_vector_type(2)));

#define T_LEN 256
#define BB    64
#define EE    256
#define HH    512
#define KK    128
#define KCAT  768   // E + H

static __device__ inline unsigned f2bf(float f) {
  union { float f; unsigned u; } v; v.f = f;
  unsigned r = v.u + 0x7FFF + ((v.u >> 16) & 1);   // round-nearest-even
  return r >> 16;
}
static __device__ inline float sigm(float x) { return 1.f / (1.f + __expf(-x)); }
static __device__ inline float tanh_fast(float x) {
  return 1.f - 2.f / (1.f + __expf(2.f * x));      // safe at +/-inf
}
static __device__ inline bf16x8 ubf(u32x4 v) {
  union { u32x4 u; bf16x8 b; } c; c.u = v; return c.b;
}

// --- 1. weight conversion (LDS tile transpose, coalesced both sides) -------
__global__ __launch_bounds__(256) void build_wcat(
    const float* __restrict__ Wi, const float* __restrict__ Wh,
    unsigned short* __restrict__ WcatT) {
  __shared__ float tile[64][65];
  int ct = blockIdx.x & 31, kt = blockIdx.x >> 5;    // 32 c-tiles x 12 k-tiles
  int tc = threadIdx.x & 63, tr = threadIdx.x >> 6;
  int c0 = ct * 64, k0 = kt * 64;
#pragma unroll
  for (int i = 0; i < 16; ++i) {
    int r = tr * 16 + i, k = k0 + r;
    float v = (k < EE) ? Wi[(size_t)k * 2048 + c0 + tc]
                       : Wh[(size_t)(k - EE) * 2048 + c0 + tc];
    tile[r][tc] = v;
  }
  __syncthreads();
#pragma unroll
  for (int i = 0; i < 16; ++i) {
    int cL = tr * 16 + i;
    WcatT[(size_t)(c0 + cL) * KCAT + k0 + tc] = (unsigned short)f2bf(tile[tc][cL]);
  }
}

__global__ __launch_bounds__(256) void build_wout(
    const float* __restrict__ Wout, unsigned short* __restrict__ WoutT) {
  __shared__ float tile[64][65];
  int ct = blockIdx.x & 1, kt = blockIdx.x >> 1;     // 2 c-tiles x 8 k-tiles
  int tc = threadIdx.x & 63, tr = threadIdx.x >> 6;
  int c0 = ct * 64, k0 = kt * 64;
#pragma unroll
  for (int i = 0; i < 16; ++i) {
    int r = tr * 16 + i;
    tile[r][tc] = Wout[(size_t)(k0 + r) * KK + c0 + tc];
  }
  __syncthreads();
#pragma unroll
  for (int i = 0; i < 16; ++i) {
    int cL = tr * 16 + i;
    WoutT[(size_t)(c0 + cL) * HH + k0 + tc] = (unsigned short)f2bf(tile[tc][cL]);
  }
}

// --- 2. embedding ----------------------------------------------------------
__global__ __launch_bounds__(256) void embed_kernel(
    const int* __restrict__ wx, const int* __restrict__ cx,
    const float* __restrict__ we, const float* __restrict__ ce,
    unsigned short* __restrict__ x) {
  int bid = blockIdx.x;             // t*64 + b
  int t = bid >> 6, b = bid & 63;
  int e = threadIdx.x;              // 0..255
  int w = wx[b * T_LEN + t];
  float v = we[(size_t)w * EE + e];
  const int* cp = cx + ((size_t)(b * T_LEN + t)) * 8;
  float s = 0.f;
#pragma unroll
  for (int l = 0; l < 8; ++l) s += ce[(size_t)cp[l] * EE + e];
  v += s * 0.125f;
  x[(size_t)bid * EE + e] = (unsigned short)f2bf(v);
}

// --- 3. flags + slot counters reset (write through to LLC) -----------------
__global__ void zero_flags(unsigned int* __restrict__ f) {   // 264 dwords
  int i = threadIdx.x;
  if (i < 264) {
    unsigned z = 0u;
    asm volatile("global_store_dword %0, %1, off sc0 sc1"
                 :: "v"(f + i), "v"(z) : "memory");
  }
}

// --- 4. persistent LSTM (XCD-replicated) -----------------------------------
#define SBAR __builtin_amdgcn_sched_barrier(0)
#define WAITV0 do { asm volatile("s_waitcnt vmcnt(0)" ::: "memory"); SBAR; } while (0)
#define LDN(dst, p, OFF) \
  asm volatile("global_load_dwordx4 %0, %1, off offset:" OFF \
               : "=v"(dst) : "v"(p) : "memory")
#define LH(dst, p, OFF) \
  asm volatile("global_load_dwordx4 %0, %1, off offset:" OFF " sc0" \
               : "=v"(dst) : "v"(p) : "memory")

#define ISSUE_X16(B, P) do { \
  LDN(B[0],P,"0");   LDN(B[1],P,"32");  LDN(B[2],P,"64");  LDN(B[3],P,"96"); \
  LDN(B[4],P,"128"); LDN(B[5],P,"160"); LDN(B[6],P,"192"); LDN(B[7],P,"224"); \
  LDN(B[8],P,"256"); LDN(B[9],P,"288"); LDN(B[10],P,"320"); LDN(B[11],P,"352"); \
  LDN(B[12],P,"384"); LDN(B[13],P,"416"); LDN(B[14],P,"448"); LDN(B[15],P,"480"); } while (0)
#define ISSUE_H8(B, P) do { \
  LH(B[16],P,"0");  LH(B[17],P,"32"); LH(B[18],P,"64"); LH(B[19],P,"96"); \
  LH(B[20],P,"128"); LH(B[21],P,"160"); LH(B[22],P,"192"); LH(B[23],P,"224"); } while (0)
#define ISSUE_H24(B, P) do { \
  LH(B[0],P,"0");   LH(B[1],P,"32");  LH(B[2],P,"64");  LH(B[3],P,"96"); \
  LH(B[4],P,"128"); LH(B[5],P,"160"); LH(B[6],P,"192"); LH(B[7],P,"224"); \
  LH(B[8],P,"256"); LH(B[9],P,"288"); LH(B[10],P,"320"); LH(B[11],P,"352"); \
  LH(B[12],P,"384"); LH(B[13],P,"416"); LH(B[14],P,"448"); LH(B[15],P,"480"); \
  LH(B[16],P,"512"); LH(B[17],P,"544"); LH(B[18],P,"576"); LH(B[19],P,"608"); \
  LH(B[20],P,"640"); LH(B[21],P,"672"); LH(B[22],P,"704"); LH(B[23],P,"736"); } while (0)

#define POLLF(TGT) do { \
    unsigned v_; int sp_ = 0; int ok_; \
    do { \
      asm volatile("global_load_dword %0, %1, off sc0\n\ts_waitcnt vmcnt(0)" \
                   : "=v"(v_) : "v"(fl + (lane & 31)) : "memory"); \
      ok_ = __all((int)(v_ >= (unsigned)(TGT))); \
    } while (!ok_ && ++sp_ < 32768); \
    SBAR; \
  } while (0)

// merge partials, gates, publish h[T+1], flag. z-final tile: kh0 -> u[ub..],
// kh1 -> u[ub..] (ub includes the +8). Gate regs: i=z[j], f=z[4+j], g=z[8+j],
// o=z[12+j] at u=ub+j (r6-verified 32x32 C layout).
#define STEP_TAIL(T) do { \
    if (kh == 0) { \
      _Pragma("unroll") \
      for (int rq = 0; rq < 4; ++rq) \
        ex[bh][0][rq][lane] = (f32x4){accB[4*rq], accB[4*rq+1], accB[4*rq+2], accB[4*rq+3]}; \
    } else { \
      _Pragma("unroll") \
      for (int rq = 0; rq < 4; ++rq) \
        ex[bh][1][rq][lane] = (f32x4){accA[4*rq], accA[4*rq+1], accA[4*rq+2], accA[4*rq+3]}; \
    } \
    __syncthreads(); \
    f32x16 z; \
    if (kh == 0) { \
      _Pragma("unroll") \
      for (int rq = 0; rq < 4; ++rq) { \
        f32x4 p = ex[bh][1][rq][lane]; \
        _Pragma("unroll") \
        for (int i = 0; i < 4; ++i) z[4*rq+i] = accA[4*rq+i] + p[i]; \
      } \
    } else { \
      _Pragma("unroll") \
      for (int rq = 0; rq < 4; ++rq) { \
        f32x4 p = ex[bh][0][rq][lane]; \
        _Pragma("unroll") \
        for (int i = 0; i < 4; ++i) z[4*rq+i] = accB[4*rq+i] + p[i]; \
      } \
    } \
    bool mk = ((int)wxv) > 0; \
    _Pragma("unroll") \
    for (int j = 0; j < 4; ++j) { \
      float zi = z[j], zf = z[4+j], zg = z[8+j], zo = z[12+j]; \
      float cn = sigm(zf) * cst[j] + sigm(zi) * tanh_fast(zg); \
      float hn = sigm(zo) * tanh_fast(cn); \
      if (mk) { cst[j] = cn; hst[j] = hn; } \
    } \
    u32x2 ph; \
    ph[0] = f2bf(hst[0]) | (f2bf(hst[1]) << 16); \
    ph[1] = f2bf(hst[2]) | (f2bf(hst[3]) << 16); \
    asm volatile("global_store_dwordx2 %0, %1, off sc0" \
                 :: "v"(hbW + (((T) + 1) & 1) * 65536), "v"(ph) : "memory"); \
    WAITV0; \
    __syncthreads(); \
    if (tid == 0) \
      asm volatile("global_store_dword %0, %1, off sc0" \
                   :: "v"(fl + slot), "v"((unsigned)((T) + 1)) : "memory"); \
    if (wr_hs) \
      asm volatile("global_store_dwordx2 %0, %1, off" \
                   :: "v"(hsW + (size_t)(T) * 65536), "v"(ph) : "memory"); \
  } while (0)

__global__ __launch_bounds__(256, 1) void lstm_persistent(
    const unsigned short* __restrict__ x,      // [T][64][256] bf16
    unsigned short* __restrict__ hs,           // [256][64][512] (slot t = h[t+1])
    unsigned short* __restrict__ hbuf,         // [8][2][64][512] bf16
    const unsigned short* __restrict__ WcatT,  // [2048][768] bf16
    const float* __restrict__ bias,            // [2048]
    const int* __restrict__ wx,                // [64][256]
    unsigned int* __restrict__ flags,          // [8][32] + ctr[8]
    unsigned int* __restrict__ ctr) {          // [8]
  __shared__ f32x4 ex[2][2][4][64];            // 16 KB partial exchange
  __shared__ int s_slot;
  __shared__ char pad[73728];                  // forces 1 block/CU (total ~88KB)
  const int tid = threadIdx.x;

  unsigned xcc;
  asm volatile("s_getreg_b32 %0, hwreg(HW_REG_XCC_ID)" : "=s"(xcc));
  xcc &= 7u;

  if (tid == 0) {
    s_slot = (int)(__hip_atomic_fetch_add(ctr + xcc, 1u,
                  __ATOMIC_RELAXED, __HIP_MEMORY_SCOPE_AGENT) & 31u);
    pad[0] = 1;                                // keep pad allocated
  }
  __syncthreads();
  const int slot = s_slot;
  const int u0 = slot * 16;

  const int wave = tid >> 6, lane = tid & 63;
  const int bh = wave & 1, kh = wave >> 1;     // batch-half, K-half
  const int hi = lane >> 5;
  const int batch = bh * 32 + (lane & 31);
  const int rr = lane & 31;
  const int kf0 = kh * 24;                     // this wave's K-frag base (of 48)

  // A-frag cols: tile0 -> u[u0..u0+8), tile1 -> u[u0+8..u0+16), each all 4 gates
  const int gcol0 = (rr >> 3) * HH + u0 + (rr & 7);
  const int gcol1 = gcol0 + 8;

  bf16x8 wA[24], wB[24];                       // 192 VGPR, loop-invariant
#pragma unroll
  for (int j = 0; j < 24; ++j) {
    wA[j] = *(const bf16x8*)(WcatT + (size_t)gcol0 * KCAT + (kf0 + j) * 16 + hi * 8);
    wB[j] = *(const bf16x8*)(WcatT + (size_t)gcol1 * KCAT + (kf0 + j) * 16 + hi * 8);
  }
  const int ub = u0 + (kh ? 8 : 0) + 4 * hi;   // this wave's final-gate u base
  float bv[16];
#pragma unroll
  for (int g = 0; g < 4; ++g)
#pragma unroll
    for (int j = 0; j < 4; ++j) bv[g * 4 + j] = bias[g * HH + ub + j];
#pragma unroll
  for (int j = 0; j < 24; ++j) { asm volatile("" :: "v"(wA[j]), "v"(wB[j])); }

  const char* xb  = (const char*)x + ((size_t)batch * EE + hi * 8) * 2;
  const char* hbR = (const char*)hbuf + (size_t)xcc * 131072 +
                    ((size_t)batch * HH + hi * 8) * 2 + (kh ? 256 : 0);
  char* hbW = (char*)hbuf + (size_t)xcc * 131072 + ((size_t)batch * HH + ub) * 2;
  char* hsW = (char*)hs + ((size_t)batch * HH + ub) * 2;
  const int* wxp = wx + batch * T_LEN;
  unsigned int* fl = flags + xcc * 32;
  const bool wr_hs = (xcc == 0);

  float cst[4] = {0.f, 0.f, 0.f, 0.f}, hst[4] = {0.f, 0.f, 0.f, 0.f};
  u32x4 buf[24];
  unsigned wxv;
  f32x16 accA, accB;

  // ---- t = 0 (h = 0: kh0 does x-part; kh1 contributes zero partial) ----
  if (kh == 0) ISSUE_X16(buf, xb);
  asm volatile("global_load_dword %0, %1, off" : "=v"(wxv) : "v"(wxp) : "memory");
  WAITV0;
#pragma unroll
  for (int i = 0; i < 16; ++i) { accA[i] = kh ? 0.f : bv[i]; accB[i] = kh ? bv[i] : 0.f; }
  if (kh == 0) {
#pragma unroll
    for (int j = 0; j < 16; ++j) {
      bf16x8 d = ubf(buf[j]);
      accA = __builtin_amdgcn_mfma_f32_32x32x16_bf16(wA[j], d, accA, 0, 0, 0);
      accB = __builtin_amdgcn_mfma_f32_32x32x16_bf16(wB[j], d, accB, 0, 0, 0);
    }
  }
  STEP_TAIL(0);

  // ---- t = 1..255 ----
  for (int t = 1; t < T_LEN; ++t) {
    const char* hsl = hbR + ((t & 1) ? 65536 : 0);
    if (kh == 0) ISSUE_X16(buf, xb + (size_t)t * 32768);
    asm volatile("global_load_dword %0, %1, off" : "=v"(wxv) : "v"(wxp + t) : "memory");
    POLLF(t);                                  // own-XCD 32 flags (L2-local)
    if (kh == 0) { ISSUE_H8(buf, hsl); } else { ISSUE_H24(buf, hsl); }
    WAITV0;
#pragma unroll
    for (int i = 0; i < 16; ++i) { accA[i] = kh ? 0.f : bv[i]; accB[i] = kh ? bv[i] : 0.f; }
#pragma unroll
    for (int j = 0; j < 24; ++j) {
      bf16x8 d = ubf(buf[j]);
      accA = __builtin_amdgcn_mfma_f32_32x32x16_bf16(wA[j], d, accA, 0, 0, 0);
      accB = __builtin_amdgcn_mfma_f32_32x32x16_bf16(wB[j], d, accB, 0, 0, 0);
    }
    STEP_TAIL(t);
  }
}

// --- 5. emissions GEMM: 256 blocks x 512 thr, 64 rows x 128 cols/block -----
__global__ __launch_bounds__(512) void em_gemm(
    const unsigned short* __restrict__ hs,    // [256][64][512] bf16
    const unsigned short* __restrict__ WoutT, // [128][512] bf16
    const float* __restrict__ bout,
    const int* __restrict__ wx,
    float* __restrict__ em) {                 // [16384][128]
  int mg = blockIdx.x;                        // 0..255
  int wave = threadIdx.x >> 6, lane = threadIdx.x & 63;
  int m = wave >> 1, nh = wave & 1;
  int arow = lane & 15, kg = (lane >> 4) * 8;
  int rbase = mg * 64 + m * 16;
  const unsigned short* A = hs + (size_t)(rbase + arow) * HH + kg;
  f32x4 acc[4];
#pragma unroll
  for (int nt = 0; nt < 4; ++nt) acc[nt] = (f32x4){0.f, 0.f, 0.f, 0.f};
#pragma unroll
  for (int ks = 0; ks < 16; ++ks) {
    bf16x8 a = *(const bf16x8*)(A + ks * 32);
#pragma unroll
    for (int nt = 0; nt < 4; ++nt) {
      const unsigned short* Bp =
          WoutT + (size_t)(nh * 64 + nt * 16 + arow) * HH + kg + ks * 32;
      acc[nt] = __builtin_amdgcn_mfma_f32_16x16x32_bf16(a, *(const bf16x8*)Bp, acc[nt], 0, 0, 0);
    }
  }
#pragma unroll
  for (int nt = 0; nt < 4; ++nt) {
    int n = nh * 64 + nt * 16 + arow;
    float bo = bout[n];
#pragma unroll
    for (int r = 0; r < 4; ++r) {
      int row = rbase + (lane >> 4) * 4 + r;  // t*64 + b
      int t = row >> 6, b = row & 63;
      float v = (acc[nt][r] + bo) * ((wx[b * T_LEN + t] > 0) ? 1.f : 0.f);
      em[(size_t)row * KK + n] = v;
    }
  }
}

// --- 6. CRF forward + gold (512 threads: k x j-quarter) ---------------------
__global__ __launch_bounds__(512) void crf_kernel(
    const float* __restrict__ em,             // [256][64][128]
    const float* __restrict__ trans,          // [128][128]
    const int* __restrict__ wx,
    const int* __restrict__ y,                // [64][257]
    float* __restrict__ out) {
  int b = blockIdx.x;
  __shared__ float tl[KK][129];
  __shared__ float sc[KK];
  __shared__ float red[512];
  __shared__ float red2[512];
  int tid = threadIdx.x;
  for (int i = tid; i < KK * KK; i += 512) tl[i >> 7][i & 127] = trans[i];
  if (tid < KK) sc[tid] = (tid == 1) ? 0.f : -10000.f;
  __syncthreads();

  int k = tid & 127, q = tid >> 7, j0 = q * 32;

  for (int t = 0; t < T_LEN; ++t) {
    if (wx[b * T_LEN + t] <= 0) continue;     // block-uniform
    float mx = -1e30f;
#pragma unroll
    for (int j = 0; j < 32; ++j) mx = fmaxf(mx, sc[j0 + j] + tl[k][j0 + j]);
    float s = 0.f;
#pragma unroll
    for (int j = 0; j < 32; ++j) s += __expf(sc[j0 + j] + tl[k][j0 + j] - mx);
    red[tid] = mx; red2[tid] = s;
    __syncthreads();
    if (q == 0) {
      float M = mx, S = s;
#pragma unroll
      for (int qq = 1; qq < 4; ++qq) {
        float m2 = red[qq * 128 + k], s2 = red2[qq * 128 + k];
        float Mn = fmaxf(M, m2);
        S = S * __expf(M - Mn) + s2 * __expf(m2 - Mn);
        M = Mn;
      }
      sc[k] = em[(size_t)(t * BB + b) * KK + k] + M + __logf(S);
    }
    __syncthreads();
  }

  // gold score
  float term = 0.f, cnt = 0.f;
  if (tid < T_LEN) {
    int yp = y[b * 257 + tid], yn = y[b * 257 + tid + 1];
    if (wx[b * T_LEN + tid] > 0) {
      term = em[(size_t)(tid * BB + b) * KK + yn] + tl[yn][yp];
      cnt = 1.f;
    }
  }
  red[tid] = term; red2[tid] = cnt;
  __syncthreads();
  for (int s2 = 256; s2 > 0; s2 >>= 1) {
    if (tid < s2) { red[tid] += red[tid + s2]; red2[tid] += red2[tid + s2]; }
    __syncthreads();
  }
  float gold = red[0];
  int len = (int)(red2[0] + 0.5f);
  __syncthreads();

  // Z = LSE_k(sc[k] + trans[EOS][k])
  float v = (tid < KK) ? sc[tid] + tl[2][tid] : -3.0e38f;
  red[tid] = v;
  __syncthreads();
  for (int s2 = 256; s2 > 0; s2 >>= 1) {
    if (tid < s2) red[tid] = fmaxf(red[tid], red[tid + s2]);
    __syncthreads();
  }
  float mz = red[0];
  __syncthreads();
  red[tid] = (tid < KK) ? __expf(v - mz) : 0.f;
  __syncthreads();
  for (int s2 = 256; s2 > 0; s2 >>= 1) {
    if (tid < s2) red[tid] += red[tid + s2];
    __syncthreads();
  }
  if (tid == 0) {
    float Z = mz + __logf(red[0]);
    int last_tag = y[b * 257 + len];
    out[b] = Z - (gold + tl[2][last_tag]);
  }
}

// ---------------------------------------------------------------------------
extern "C" void kernel_launch(void* const* d_in, const int* in_sizes, int n_in,
                              void* d_out, int out_size, void* d_ws, size_t ws_size,
                              hipStream_t stream) {
  const int*   cx    = (const int*)d_in[0];
  const int*   wx    = (const int*)d_in[1];
  const int*   y     = (const int*)d_in[2];
  const float* ce    = (const float*)d_in[3];
  const float* we    = (const float*)d_in[4];
  const float* Wi    = (const float*)d_in[5];
  const float* Wh    = (const float*)d_in[6];
  const float* bias  = (const float*)d_in[7];
  const float* Wout  = (const float*)d_in[8];
  const float* bout  = (const float*)d_in[9];
  const float* trans = (const float*)d_in[10];
  float* out = (float*)d_out;

  char* ws = (char*)d_ws;
  // ws layout (16B aligned), ~29.5 MB; em aliases x (x dead after lstm)
  unsigned short* WcatT = (unsigned short*)(ws + 0);          //  3,145,728
  unsigned short* WoutT = (unsigned short*)(ws + 3145728);    //    131,072
  unsigned short* x     = (unsigned short*)(ws + 3276800);    //  8,388,608
  unsigned short* hs    = (unsigned short*)(ws + 11665408);   // 16,777,216
  unsigned short* hbuf  = (unsigned short*)(ws + 28442624);   //  1,048,576
  unsigned int*   flags = (unsigned int*)(ws + 29491200);     //  1,024
  unsigned int*   ctr   = (unsigned int*)(ws + 29492224);     //     32
  float*          em    = (float*)(ws + 3276800);             //  8,388,608 (alias x)

  build_wcat<<<384, 256, 0, stream>>>(Wi, Wh, WcatT);
  build_wout<<<16, 256, 0, stream>>>(Wout, WoutT);
  embed_kernel<<<T_LEN * BB, 256, 0, stream>>>(wx, cx, we, ce, x);
  zero_flags<<<1, 512, 0, stream>>>(flags);    // flags[8][32] + ctr[8] contiguous
  lstm_persistent<<<256, 256, 0, stream>>>(x, hs, hbuf, WcatT, bias, wx, flags, ctr);
  em_gemm<<<256, 512, 0, stream>>>(hs, WoutT, bout, wx, em);
  crf_kernel<<<BB, 512, 0, stream>>>(em, trans, wx, y, out);
}

// Round 8
// 2357.633 us; speedup vs baseline: 289.9874x; 289.9874x over previous
//
#include <hip/hip_runtime.h>

// ---------------------------------------------------------------------------
// RNN (LSTM) + CRF loss on MI355X — round 8.
// LSTM: 64 persistent blocks x 128 thr, 32x32x16 swapped MFMA (r6-proven
// layout/protocol). Changes vs r6: flags at 64B stride; wave0-only poll with
// s_sleep backoff + bailout; ALL loads (x, h, streamed weights) issued after
// the poll in a 6-stage counted-vmcnt pipeline; mask bits preloaded.
// ---------------------------------------------------------------------------

typedef float f32x4 __attribute__((ext_vector_type(4)));
typedef float f32x16 __attribute__((ext_vector_type(16)));
typedef __bf16 bf16x8 __attribute__((ext_vector_type(8)));
typedef unsigned int u32x2 __attribute__((ext_vector_type(2)));

#define T_LEN 256
#define BB    64
#define EE    256
#define HH    512
#define KK    128
#define KCAT  768   // E + H

static __device__ inline unsigned f2bf(float f) {
  union { float f; unsigned u; } v; v.f = f;
  unsigned r = v.u + 0x7FFF + ((v.u >> 16) & 1);   // round-nearest-even
  return r >> 16;
}
static __device__ inline float sigm(float x) { return 1.f / (1.f + __expf(-x)); }
static __device__ inline float tanh_fast(float x) {
  return 1.f - 2.f / (1.f + __expf(2.f * x));      // safe at +/-inf
}

// --- 1. weight conversion (LDS tile transpose, coalesced both sides) -------
__global__ __launch_bounds__(256) void build_wcat(
    const float* __restrict__ Wi, const float* __restrict__ Wh,
    unsigned short* __restrict__ WcatT) {
  __shared__ float tile[64][65];
  int ct = blockIdx.x & 31, kt = blockIdx.x >> 5;    // 32 c-tiles x 12 k-tiles
  int tc = threadIdx.x & 63, tr = threadIdx.x >> 6;
  int c0 = ct * 64, k0 = kt * 64;
#pragma unroll
  for (int i = 0; i < 16; ++i) {
    int r = tr * 16 + i, k = k0 + r;
    float v = (k < EE) ? Wi[(size_t)k * 2048 + c0 + tc]
                       : Wh[(size_t)(k - EE) * 2048 + c0 + tc];
    tile[r][tc] = v;
  }
  __syncthreads();
#pragma unroll
  for (int i = 0; i < 16; ++i) {
    int cL = tr * 16 + i;
    WcatT[(size_t)(c0 + cL) * KCAT + k0 + tc] = (unsigned short)f2bf(tile[tc][cL]);
  }
}

__global__ __launch_bounds__(256) void build_wout(
    const float* __restrict__ Wout, unsigned short* __restrict__ WoutT) {
  __shared__ float tile[64][65];
  int ct = blockIdx.x & 1, kt = blockIdx.x >> 1;     // 2 c-tiles x 8 k-tiles
  int tc = threadIdx.x & 63, tr = threadIdx.x >> 6;
  int c0 = ct * 64, k0 = kt * 64;
#pragma unroll
  for (int i = 0; i < 16; ++i) {
    int r = tr * 16 + i;
    tile[r][tc] = Wout[(size_t)(k0 + r) * KK + c0 + tc];
  }
  __syncthreads();
#pragma unroll
  for (int i = 0; i < 16; ++i) {
    int cL = tr * 16 + i;
    WoutT[(size_t)(c0 + cL) * HH + k0 + tc] = (unsigned short)f2bf(tile[tc][cL]);
  }
}

// --- 2. embedding ----------------------------------------------------------
__global__ __launch_bounds__(256) void embed_kernel(
    const int* __restrict__ wx, const int* __restrict__ cx,
    const float* __restrict__ we, const float* __restrict__ ce,
    unsigned short* __restrict__ x) {
  int bid = blockIdx.x;             // t*64 + b
  int t = bid >> 6, b = bid & 63;
  int e = threadIdx.x;              // 0..255
  int w = wx[b * T_LEN + t];
  float v = we[(size_t)w * EE + e];
  const int* cp = cx + ((size_t)(b * T_LEN + t)) * 8;
  float s = 0.f;
#pragma unroll
  for (int l = 0; l < 8; ++l) s += ce[(size_t)cp[l] * EE + e];
  v += s * 0.125f;
  x[(size_t)bid * EE + e] = (unsigned short)f2bf(v);
}

// --- 3. flag reset (sc0 sc1 so LLC-bypass poll loads see the zeros) --------
__global__ void zero_flags(unsigned int* __restrict__ f) {   // 1024 dwords
  unsigned z = 0u;
  asm volatile("global_store_dword %0, %1, off sc0 sc1"
               :: "v"(f + blockIdx.x * 256 + threadIdx.x), "v"(z) : "memory");
}

// --- 4. persistent LSTM ----------------------------------------------------
#define SBAR __builtin_amdgcn_sched_barrier(0)
#define WAITV(N) do { asm volatile("s_waitcnt vmcnt(" #N ")" ::: "memory"); SBAR; } while (0)
#define LD(dst, p, OFF) \
  asm volatile("global_load_dwordx4 %0, %1, off offset:" OFF \
               : "=v"(dst) : "v"(p) : "memory")
#define LS(dst, p, OFF) \
  asm volatile("global_load_dwordx4 %0, %1, off offset:" OFF " sc0 sc1" \
               : "=v"(dst) : "v"(p) : "memory")

#define IS_P8(B, P) do { \
  LD(B[0],P,"0");   LD(B[1],P,"32");  LD(B[2],P,"64");  LD(B[3],P,"96"); \
  LD(B[4],P,"128"); LD(B[5],P,"160"); LD(B[6],P,"192"); LD(B[7],P,"224"); } while (0)
#define IS_S8(B, P) do { \
  LS(B[0],P,"0");   LS(B[1],P,"32");  LS(B[2],P,"64");  LS(B[3],P,"96"); \
  LS(B[4],P,"128"); LS(B[5],P,"160"); LS(B[6],P,"192"); LS(B[7],P,"224"); } while (0)

#define MFMA8(W, D) do { \
  _Pragma("unroll") \
  for (int j_ = 0; j_ < 8; ++j_) \
    acc = __builtin_amdgcn_mfma_f32_32x32x16_bf16(W[j_], D[j_], acc, 0, 0, 0); \
  } while (0)

// wave = 32 batches x 32 z-cols (32x32x16 swapped MFMA, D = Wfrag x Hfrag).
// acc[g*4+j] = gate g, u = u0 + 4*hi + j (r6-verified C layout).
__global__ __launch_bounds__(128, 1) void lstm_persistent(
    const unsigned short* __restrict__ x,      // [T][64][256] bf16
    unsigned short* __restrict__ hs,           // [256][64][512] (slot t = h[t+1])
    const unsigned short* __restrict__ WcatT,  // [2048][768] bf16
    const float* __restrict__ bias,            // [2048]
    const int* __restrict__ wx,                // [64][256]
    unsigned int* __restrict__ flags) {        // 64 flags, 64B stride
  const int tid = threadIdx.x;
  const int wave = tid >> 6, lane = tid & 63;
  const int hi2 = lane >> 5;
  const int batch = wave * 32 + (lane & 31);
  const int u0 = blockIdx.x * 8;               // block's u-slice [u0, u0+8)
  const int rr = lane & 31;
  const int col = (rr >> 3) * HH + u0 + (rr & 7);   // gate*512 + u0 + uoff

  const char* wbase = (const char*)WcatT + ((size_t)col * KCAT + hi2 * 8) * 2;
  const char* xp    = (const char*)x + ((size_t)batch * EE + hi2 * 8) * 2;
  const char* hp    = (const char*)hs + ((size_t)batch * HH + hi2 * 8) * 2;
  char*       hstp  = (char*)hs + ((size_t)batch * HH + u0 + 4 * hi2) * 2;
  unsigned int* myflag = flags + blockIdx.x * 16;

  float bv[16];
#pragma unroll
  for (int g = 0; g < 4; ++g)
#pragma unroll
    for (int j = 0; j < 4; ++j) bv[g * 4 + j] = bias[g * HH + u0 + 4 * hi2 + j];

  // mask bits: m8[w] bit k = (wx[batch][w*32+k] > 0)
  const int* wxp = wx + batch * T_LEN;
  unsigned m8[8];
#pragma unroll
  for (int w8 = 0; w8 < 8; ++w8) {
    unsigned m = 0;
#pragma unroll
    for (int k2 = 0; k2 < 32; ++k2)
      m |= (wxp[w8 * 32 + k2] > 0) ? (1u << k2) : 0u;
    m8[w8] = m;
  }

  float cst[4] = {0.f, 0.f, 0.f, 0.f}, hst[4] = {0.f, 0.f, 0.f, 0.f};
  bf16x8 WA[8], DA[8], WB[8], DB[8];
  f32x16 acc;

#pragma unroll
  for (int ph = 0; ph < 8; ++ph) {             // 8 mask words (static index)
    const unsigned mw = m8[ph];
#pragma unroll 1
    for (int tt = 0; tt < 32; ++tt) {          // runtime inner loop
      const int t = ph * 32 + tt;
      const bool mk = (mw >> tt) & 1u;

      if (t > 0) {
        if (wave == 0) {                       // wave0-only poll
          unsigned v_; int it_ = 0;
          for (;;) {
            asm volatile("global_load_dword %0, %1, off sc0 sc1\n\ts_waitcnt vmcnt(0)"
                         : "=v"(v_) : "v"(flags + lane * 16) : "memory");
            if (__all((int)(v_ >= (unsigned)t))) break;
            if (++it_ >= 65536) break;         // bailout: fail visibly, never hang
            __builtin_amdgcn_s_sleep(1);
          }
          SBAR;
        }
        __syncthreads();
      }

      const char* xt = xp + (size_t)t * 32768;
      const char* ht = hp + (size_t)(t - 1) * 65536;

      // 6-stage pipeline: c0,c1 = x-part; c2..c5 = h-part. W streamed (L2-hot).
      IS_P8(WA, wbase);         IS_P8(DA, xt);          // c0
      IS_P8(WB, (wbase + 256)); IS_P8(DB, (xt + 256));  // c1 (32 out)
#pragma unroll
      for (int i = 0; i < 16; ++i) acc[i] = bv[i];
      WAITV(16);  MFMA8(WA, DA);                        // c0
      if (t > 0) {
        IS_P8(WA, (wbase + 512));  IS_S8(DA, ht);           // c2
        WAITV(16);  MFMA8(WB, DB);                          // c1
        IS_P8(WB, (wbase + 768));  IS_S8(DB, (ht + 256));   // c3
        WAITV(16);  MFMA8(WA, DA);                          // c2
        IS_P8(WA, (wbase + 1024)); IS_S8(DA, (ht + 512));   // c4
        WAITV(16);  MFMA8(WB, DB);                          // c3
        IS_P8(WB, (wbase + 1280)); IS_S8(DB, (ht + 768));   // c5
        WAITV(16);  MFMA8(WA, DA);                          // c4
        WAITV(0);   MFMA8(WB, DB);                          // c5
      } else {
        WAITV(0);   MFMA8(WB, DB);                          // c1
      }

      // gates + publish h[t+1]
#pragma unroll
      for (int r = 0; r < 4; ++r) {
        float zi = acc[r], zf = acc[4 + r], zg = acc[8 + r], zo = acc[12 + r];
        float cn = sigm(zf) * cst[r] + sigm(zi) * tanh_fast(zg);
        float hn = sigm(zo) * tanh_fast(cn);
        if (mk) { cst[r] = cn; hst[r] = hn; }
      }
      u32x2 phh;
      phh[0] = f2bf(hst[0]) | (f2bf(hst[1]) << 16);
      phh[1] = f2bf(hst[2]) | (f2bf(hst[3]) << 16);
      asm volatile("global_store_dwordx2 %0, %1, off sc0 sc1"
                   :: "v"(hstp + (size_t)t * 65536), "v"(phh) : "memory");
      WAITV(0);                                // h[t+1] ack'd at LLC
      __syncthreads();                         // both waves drained
      if (tid == 0)
        asm volatile("global_store_dword %0, %1, off sc0 sc1"
                     :: "v"(myflag), "v"((unsigned)(t + 1)) : "memory");
    }
  }
}

// --- 5. emissions GEMM: 256 blocks x 512 thr, 64 rows x 128 cols/block -----
__global__ __launch_bounds__(512) void em_gemm(
    const unsigned short* __restrict__ hs,    // [256][64][512] bf16
    const unsigned short* __restrict__ WoutT, // [128][512] bf16
    const float* __restrict__ bout,
    const int* __restrict__ wx,
    float* __restrict__ em) {                 // [16384][128]
  int mg = blockIdx.x;                        // 0..255
  int wave = threadIdx.x >> 6, lane = threadIdx.x & 63;
  int m = wave >> 1, nh = wave & 1;
  int arow = lane & 15, kg = (lane >> 4) * 8;
  int rbase = mg * 64 + m * 16;
  const unsigned short* A = hs + (size_t)(rbase + arow) * HH + kg;
  f32x4 acc[4];
#pragma unroll
  for (int nt = 0; nt < 4; ++nt) acc[nt] = (f32x4){0.f, 0.f, 0.f, 0.f};
#pragma unroll
  for (int ks = 0; ks < 16; ++ks) {
    bf16x8 a = *(const bf16x8*)(A + ks * 32);
#pragma unroll
    for (int nt = 0; nt < 4; ++nt) {
      const unsigned short* Bp =
          WoutT + (size_t)(nh * 64 + nt * 16 + arow) * HH + kg + ks * 32;
      acc[nt] = __builtin_amdgcn_mfma_f32_16x16x32_bf16(a, *(const bf16x8*)Bp, acc[nt], 0, 0, 0);
    }
  }
#pragma unroll
  for (int nt = 0; nt < 4; ++nt) {
    int n = nh * 64 + nt * 16 + arow;
    float bo = bout[n];
#pragma unroll
    for (int r = 0; r < 4; ++r) {
      int row = rbase + (lane >> 4) * 4 + r;  // t*64 + b
      int t = row >> 6, b = row & 63;
      float v = (acc[nt][r] + bo) * ((wx[b * T_LEN + t] > 0) ? 1.f : 0.f);
      em[(size_t)row * KK + n] = v;
    }
  }
}

// --- 6. CRF forward + gold (512 threads: k x j-quarter) ---------------------
__global__ __launch_bounds__(512) void crf_kernel(
    const float* __restrict__ em,             // [256][64][128]
    const float* __restrict__ trans,          // [128][128]
    const int* __restrict__ wx,
    const int* __restrict__ y,                // [64][257]
    float* __restrict__ out) {
  int b = blockIdx.x;
  __shared__ float tl[KK][129];
  __shared__ float sc[KK];
  __shared__ float red[512];
  __shared__ float red2[512];
  int tid = threadIdx.x;
  for (int i = tid; i < KK * KK; i += 512) tl[i >> 7][i & 127] = trans[i];
  if (tid < KK) sc[tid] = (tid == 1) ? 0.f : -10000.f;
  __syncthreads();

  int k = tid & 127, q = tid >> 7, j0 = q * 32;

  for (int t = 0; t < T_LEN; ++t) {
    if (wx[b * T_LEN + t] <= 0) continue;     // block-uniform
    float mx = -1e30f;
#pragma unroll
    for (int j = 0; j < 32; ++j) mx = fmaxf(mx, sc[j0 + j] + tl[k][j0 + j]);
    float s = 0.f;
#pragma unroll
    for (int j = 0; j < 32; ++j) s += __expf(sc[j0 + j] + tl[k][j0 + j] - mx);
    red[tid] = mx; red2[tid] = s;
    __syncthreads();
    if (q == 0) {
      float M = mx, S = s;
#pragma unroll
      for (int qq = 1; qq < 4; ++qq) {
        float m2 = red[qq * 128 + k], s2 = red2[qq * 128 + k];
        float Mn = fmaxf(M, m2);
        S = S * __expf(M - Mn) + s2 * __expf(m2 - Mn);
        M = Mn;
      }
      sc[k] = em[(size_t)(t * BB + b) * KK + k] + M + __logf(S);
    }
    __syncthreads();
  }

  // gold score
  float term = 0.f, cnt = 0.f;
  if (tid < T_LEN) {
    int yp = y[b * 257 + tid], yn = y[b * 257 + tid + 1];
    if (wx[b * T_LEN + tid] > 0) {
      term = em[(size_t)(tid * BB + b) * KK + yn] + tl[yn][yp];
      cnt = 1.f;
    }
  }
  red[tid] = term; red2[tid] = cnt;
  __syncthreads();
  for (int s2 = 256; s2 > 0; s2 >>= 1) {
    if (tid < s2) { red[tid] += red[tid + s2]; red2[tid] += red2[tid + s2]; }
    __syncthreads();
  }
  float gold = red[0];
  int len = (int)(red2[0] + 0.5f);
  __syncthreads();

  // Z = LSE_k(sc[k] + trans[EOS][k])
  float v = (tid < KK) ? sc[tid] + tl[2][tid] : -3.0e38f;
  red[tid] = v;
  __syncthreads();
  for (int s2 = 256; s2 > 0; s2 >>= 1) {
    if (tid < s2) red[tid] = fmaxf(red[tid], red[tid + s2]);
    __syncthreads();
  }
  float mz = red[0];
  __syncthreads();
  red[tid] = (tid < KK) ? __expf(v - mz) : 0.f;
  __syncthreads();
  for (int s2 = 256; s2 > 0; s2 >>= 1) {
    if (tid < s2) red[tid] += red[tid + s2];
    __syncthreads();
  }
  if (tid == 0) {
    float Z = mz + __logf(red[0]);
    int last_tag = y[b * 257 + len];
    out[b] = Z - (gold + tl[2][last_tag]);
  }
}

// ---------------------------------------------------------------------------
extern "C" void kernel_launch(void* const* d_in, const int* in_sizes, int n_in,
                              void* d_out, int out_size, void* d_ws, size_t ws_size,
                              hipStream_t stream) {
  const int*   cx    = (const int*)d_in[0];
  const int*   wx    = (const int*)d_in[1];
  const int*   y     = (const int*)d_in[2];
  const float* ce    = (const float*)d_in[3];
  const float* we    = (const float*)d_in[4];
  const float* Wi    = (const float*)d_in[5];
  const float* Wh    = (const float*)d_in[6];
  const float* bias  = (const float*)d_in[7];
  const float* Wout  = (const float*)d_in[8];
  const float* bout  = (const float*)d_in[9];
  const float* trans = (const float*)d_in[10];
  float* out = (float*)d_out;

  char* ws = (char*)d_ws;
  // ws layout (16B aligned), ~28.5 MB; em aliases x (x dead after lstm)
  unsigned short* WcatT = (unsigned short*)(ws + 0);          //  3,145,728
  unsigned short* WoutT = (unsigned short*)(ws + 3145728);    //    131,072
  unsigned short* x     = (unsigned short*)(ws + 3276800);    //  8,388,608
  unsigned short* hs    = (unsigned short*)(ws + 11665408);   // 16,777,216
  unsigned int*   flags = (unsigned int*)(ws + 28442624);     //  4,096 B
  float*          em    = (float*)(ws + 3276800);             //  8,388,608 (alias x)

  build_wcat<<<384, 256, 0, stream>>>(Wi, Wh, WcatT);
  build_wout<<<16, 256, 0, stream>>>(Wout, WoutT);
  embed_kernel<<<T_LEN * BB, 256, 0, stream>>>(wx, cx, we, ce, x);
  zero_flags<<<4, 256, 0, stream>>>(flags);
  lstm_persistent<<<64, 128, 0, stream>>>(x, hs, WcatT, bias, wx, flags);
  em_gemm<<<256, 512, 0, stream>>>(hs, WoutT, bout, wx, em);
  crf_kernel<<<BB, 512, 0, stream>>>(em, trans, wx, y, out);
}

// Round 10
// 1739.361 us; speedup vs baseline: 393.0663x; 1.3555x over previous
//
#include <hip/hip_runtime.h>

// ---------------------------------------------------------------------------
// RNN (LSTM) + CRF loss on MI355X — round 10.
// LSTM: r6 VERBATIM (proven 1414us): 64 blocks x 128 thr, 32x32x16 swapped
// MFMA, flag handshake (h store sc0sc1 -> vmcnt ack -> syncthreads -> flag;
// consumers poll 64 flags, 1 dword/lane). CRF: NEW — E=exp(trans) precomputed
// in LDS, p=exp(sc-msc) computed once/step by 128 threads, inner loop is 32
// FMA/thread (was 32 expf/thread); msc maintained via wave shuffle-max.
// ---------------------------------------------------------------------------

typedef float f32x4 __attribute__((ext_vector_type(4)));
typedef float f32x16 __attribute__((ext_vector_type(16)));
typedef __bf16 bf16x8 __attribute__((ext_vector_type(8)));
typedef unsigned int u32x4 __attribute__((ext_vector_type(4)));
typedef unsigned int u32x2 __attribute__((ext_vector_type(2)));

#define T_LEN 256
#define BB    64
#define EE    256
#define HH    512
#define KK    128
#define KCAT  768   // E + H

static __device__ inline unsigned f2bf(float f) {
  union { float f; unsigned u; } v; v.f = f;
  unsigned r = v.u + 0x7FFF + ((v.u >> 16) & 1);   // round-nearest-even
  return r >> 16;
}
static __device__ inline float sigm(float x) { return 1.f / (1.f + __expf(-x)); }
static __device__ inline float tanh_fast(float x) {
  return 1.f - 2.f / (1.f + __expf(2.f * x));      // safe at +/-inf
}
static __device__ inline bf16x8 ubf(u32x4 v) {
  union { u32x4 u; bf16x8 b; } c; c.u = v; return c.b;
}

// --- 1. weight conversion (LDS tile transpose, coalesced both sides) -------
__global__ __launch_bounds__(256) void build_wcat(
    const float* __restrict__ Wi, const float* __restrict__ Wh,
    unsigned short* __restrict__ WcatT) {
  __shared__ float tile[64][65];
  int ct = blockIdx.x & 31, kt = blockIdx.x >> 5;    // 32 c-tiles x 12 k-tiles
  int tc = threadIdx.x & 63, tr = threadIdx.x >> 6;
  int c0 = ct * 64, k0 = kt * 64;
#pragma unroll
  for (int i = 0; i < 16; ++i) {
    int r = tr * 16 + i, k = k0 + r;
    float v = (k < EE) ? Wi[(size_t)k * 2048 + c0 + tc]
                       : Wh[(size_t)(k - EE) * 2048 + c0 + tc];
    tile[r][tc] = v;
  }
  __syncthreads();
#pragma unroll
  for (int i = 0; i < 16; ++i) {
    int cL = tr * 16 + i;
    WcatT[(size_t)(c0 + cL) * KCAT + k0 + tc] = (unsigned short)f2bf(tile[tc][cL]);
  }
}

__global__ __launch_bounds__(256) void build_wout(
    const float* __restrict__ Wout, unsigned short* __restrict__ WoutT) {
  __shared__ float tile[64][65];
  int ct = blockIdx.x & 1, kt = blockIdx.x >> 1;     // 2 c-tiles x 8 k-tiles
  int tc = threadIdx.x & 63, tr = threadIdx.x >> 6;
  int c0 = ct * 64, k0 = kt * 64;
#pragma unroll
  for (int i = 0; i < 16; ++i) {
    int r = tr * 16 + i;
    tile[r][tc] = Wout[(size_t)(k0 + r) * KK + c0 + tc];
  }
  __syncthreads();
#pragma unroll
  for (int i = 0; i < 16; ++i) {
    int cL = tr * 16 + i;
    WoutT[(size_t)(c0 + cL) * HH + k0 + tc] = (unsigned short)f2bf(tile[tc][cL]);
  }
}

// --- 2. embedding ----------------------------------------------------------
__global__ __launch_bounds__(256) void embed_kernel(
    const int* __restrict__ wx, const int* __restrict__ cx,
    const float* __restrict__ we, const float* __restrict__ ce,
    unsigned short* __restrict__ x) {
  int bid = blockIdx.x;             // t*64 + b
  int t = bid >> 6, b = bid & 63;
  int e = threadIdx.x;              // 0..255
  int w = wx[b * T_LEN + t];
  float v = we[(size_t)w * EE + e];
  const int* cp = cx + ((size_t)(b * T_LEN + t)) * 8;
  float s = 0.f;
#pragma unroll
  for (int l = 0; l < 8; ++l) s += ce[(size_t)cp[l] * EE + e];
  v += s * 0.125f;
  x[(size_t)bid * EE + e] = (unsigned short)f2bf(v);
}

// --- 3. flag reset (sc0 sc1 so LLC-bypass poll loads see the zeros) --------
__global__ void zero_flags(unsigned int* __restrict__ f) {
  unsigned z = 0u;
  asm volatile("global_store_dword %0, %1, off sc0 sc1"
               :: "v"(f + threadIdx.x), "v"(z) : "memory");
}

// --- 4. persistent LSTM (r6 VERBATIM) ---------------------------------------
#define SBAR __builtin_amdgcn_sched_barrier(0)
#define WAITV(N) do { asm volatile("s_waitcnt vmcnt(" #N ")" ::: "memory"); SBAR; } while (0)
#define LDC(dst, ptr, OFF) \
  asm volatile("global_load_dwordx4 %0, %1, off offset:" OFF " sc0 sc1" \
               : "=v"(dst) : "v"(ptr) : "memory")
#define LDN(dst, ptr, OFF) \
  asm volatile("global_load_dwordx4 %0, %1, off offset:" OFF \
               : "=v"(dst) : "v"(ptr) : "memory")

#define ISSUE_X(B, P) do { \
  LDN(B[0],P,"0");   LDN(B[1],P,"32");  LDN(B[2],P,"64");  LDN(B[3],P,"96"); \
  LDN(B[4],P,"128"); LDN(B[5],P,"160"); LDN(B[6],P,"192"); LDN(B[7],P,"224"); \
  LDN(B[8],P,"256"); LDN(B[9],P,"288"); LDN(B[10],P,"320"); LDN(B[11],P,"352"); \
  LDN(B[12],P,"384"); LDN(B[13],P,"416"); LDN(B[14],P,"448"); LDN(B[15],P,"480"); } while (0)
#define ISSUE_H0(B, P) do { \
  LDC(B[0],P,"0");   LDC(B[1],P,"32");  LDC(B[2],P,"64");  LDC(B[3],P,"96"); \
  LDC(B[4],P,"128"); LDC(B[5],P,"160"); LDC(B[6],P,"192"); LDC(B[7],P,"224"); \
  LDC(B[8],P,"256"); LDC(B[9],P,"288"); LDC(B[10],P,"320"); LDC(B[11],P,"352"); \
  LDC(B[12],P,"384"); LDC(B[13],P,"416"); LDC(B[14],P,"448"); LDC(B[15],P,"480"); } while (0)
#define ISSUE_H1(B, P) do { \
  LDC(B[0],P,"512"); LDC(B[1],P,"544"); LDC(B[2],P,"576"); LDC(B[3],P,"608"); \
  LDC(B[4],P,"640"); LDC(B[5],P,"672"); LDC(B[6],P,"704"); LDC(B[7],P,"736"); \
  LDC(B[8],P,"768"); LDC(B[9],P,"800"); LDC(B[10],P,"832"); LDC(B[11],P,"864"); \
  LDC(B[12],P,"896"); LDC(B[13],P,"928"); LDC(B[14],P,"960"); LDC(B[15],P,"992"); } while (0)

#define GATES_STORE(T) do { \
    bool mk = ((int)wxv) > 0; \
    _Pragma("unroll") \
    for (int r = 0; r < 4; ++r) { \
      float zi = acc[r], zf = acc[4 + r], zg = acc[8 + r], zo = acc[12 + r]; \
      float cn = sigm(zf) * cst[r] + sigm(zi) * tanh_fast(zg); \
      float hn = sigm(zo) * tanh_fast(cn); \
      if (mk) { cst[r] = cn; hst[r] = hn; } \
    } \
    u32x2 ph; \
    ph[0] = f2bf(hst[0]) | (f2bf(hst[1]) << 16); \
    ph[1] = f2bf(hst[2]) | (f2bf(hst[3]) << 16); \
    asm volatile("global_store_dwordx2 %0, %1, off sc0 sc1" \
                 :: "v"(hstore + (size_t)(T) * 65536), "v"(ph) : "memory"); \
  } while (0)

// wave = 32 batches x 32 z-cols (32x32x16 swapped MFMA, D = Wfrag x Hfrag).
// D: col = lane&31 (batch), row = (reg&3) + 8*(reg>>2) + 4*(lane>>5)
//    = gate*8 + uoff  -> acc[g*4+r] = gate g, u = u0 + 4*hi + r. All 4 gates
// in-lane; weight A-frags (rows = z-cols) loop-invariant in 192 VGPRs.
__global__ __launch_bounds__(128, 1) void lstm_persistent(
    const unsigned short* __restrict__ x,      // [T][64][256] bf16
    unsigned short* __restrict__ hs,           // [256][64][512] bf16 (slot t = h[t+1])
    const unsigned short* __restrict__ WcatT,  // [2048][768] bf16
    const float* __restrict__ bias,            // [2048]
    const int* __restrict__ wx,                // [64][256]
    unsigned int* __restrict__ flags) {        // 64 packed dwords
  const int tid = threadIdx.x;
  const int lane = tid & 63;
  const int bhalf = tid >> 6;                  // 2 waves: batch halves
  const int hi = lane >> 5;
  const int batch = bhalf * 32 + (lane & 31);
  const int u0 = blockIdx.x * 8;               // block's u-slice [u0, u0+8)
  const int rr = lane & 31;                    // A-frag row = z-col id
  const int wcol = (rr >> 3) * HH + u0 + (rr & 7);   // gate*512 + u0 + uoff

  // 48 loop-invariant weight A-frags -> 192 VGPRs
  bf16x8 wreg[48];
#pragma unroll
  for (int kf = 0; kf < 48; ++kf)
    wreg[kf] = *(const bf16x8*)(WcatT + (size_t)wcol * KCAT + kf * 16 + hi * 8);

  float bv[16];
#pragma unroll
  for (int q = 0; q < 4; ++q)
#pragma unroll
    for (int r = 0; r < 4; ++r)
      bv[q * 4 + r] = bias[q * HH + u0 + 4 * hi + r];

  const char* xlane  = (const char*)x  + ((size_t)batch * EE + hi * 8) * 2;
  const char* hread  = (const char*)hs + ((size_t)batch * HH + hi * 8) * 2;
  char*       hstore = (char*)hs + ((size_t)batch * HH + u0 + 4 * hi) * 2;
  const int*  wxp    = wx + batch * T_LEN;

  float cst[4] = {0.f, 0.f, 0.f, 0.f};
  float hst[4] = {0.f, 0.f, 0.f, 0.f};
  u32x4 bufX[16], bufH[16];
  unsigned wxv;
  f32x16 acc;

  // ---- t = 0 (h = 0: x-part only) ----
  ISSUE_X(bufX, xlane);
  asm volatile("global_load_dword %0, %1, off" : "=v"(wxv) : "v"(wxp) : "memory");
  WAITV(0);
#pragma unroll
  for (int i = 0; i < 16; ++i) acc[i] = bv[i];
#pragma unroll
  for (int kf = 0; kf < 16; ++kf)
    acc = __builtin_amdgcn_mfma_f32_32x32x16_bf16(wreg[kf], ubf(bufX[kf]), acc, 0, 0, 0);
  GATES_STORE(0);
  WAITV(0);                                    // h[1] ack'd at LLC
  __syncthreads();
  if (tid == 0)
    __hip_atomic_store(flags + blockIdx.x, 1u, __ATOMIC_RELAXED, __HIP_MEMORY_SCOPE_AGENT);

  // ---- t = 1..255 ----
  for (int t = 1; t < T_LEN; ++t) {
    const char* xt = xlane + (size_t)t * 32768;
    const char* hp = hread + (size_t)(t - 1) * 65536;

    ISSUE_X(bufX, xt);
    asm volatile("global_load_dword %0, %1, off" : "=v"(wxv) : "v"(wxp + t) : "memory");
    // poll 64 packed producer flags: one coalesced dword per lane
    {
      unsigned v;
      do {
        asm volatile("global_load_dword %0, %1, off sc0 sc1\n\ts_waitcnt vmcnt(0)"
                     : "=v"(v) : "v"(flags + lane) : "memory");
      } while (!__all((int)(v >= (unsigned)t)));
      SBAR;
    }
    ISSUE_H0(bufH, hp);                        // h chunk 0 in flight
#pragma unroll
    for (int i = 0; i < 16; ++i) acc[i] = bv[i];
#pragma unroll
    for (int kf = 0; kf < 16; ++kf)            // x-part (data arrived: poll drained)
      acc = __builtin_amdgcn_mfma_f32_32x32x16_bf16(wreg[kf], ubf(bufX[kf]), acc, 0, 0, 0);
    SBAR;
    ISSUE_H1(bufX, hp);                        // h chunk 1 reuses x buffer
    WAITV(16);                                 // chunk 0 arrived
#pragma unroll
    for (int kf = 0; kf < 16; ++kf)
      acc = __builtin_amdgcn_mfma_f32_32x32x16_bf16(wreg[16 + kf], ubf(bufH[kf]), acc, 0, 0, 0);
    WAITV(0);                                  // chunk 1 arrived
#pragma unroll
    for (int kf = 0; kf < 16; ++kf)
      acc = __builtin_amdgcn_mfma_f32_32x32x16_bf16(wreg[32 + kf], ubf(bufX[kf]), acc, 0, 0, 0);
    GATES_STORE(t);
    WAITV(0);                                  // h[t+1] ack'd at LLC
    __syncthreads();                           // both waves drained
    if (tid == 0)
      __hip_atomic_store(flags + blockIdx.x, (unsigned)(t + 1),
                         __ATOMIC_RELAXED, __HIP_MEMORY_SCOPE_AGENT);
  }
}

// --- 5. emissions GEMM: 256 blocks x 512 thr, 64 rows x 128 cols/block -----
__global__ __launch_bounds__(512) void em_gemm(
    const unsigned short* __restrict__ hs,    // [256][64][512] bf16
    const unsigned short* __restrict__ WoutT, // [128][512] bf16
    const float* __restrict__ bout,
    const int* __restrict__ wx,
    float* __restrict__ em) {                 // [16384][128]
  int mg = blockIdx.x;                        // 0..255
  int wave = threadIdx.x >> 6, lane = threadIdx.x & 63;
  int m = wave >> 1, nh = wave & 1;
  int arow = lane & 15, kg = (lane >> 4) * 8;
  int rbase = mg * 64 + m * 16;
  const unsigned short* A = hs + (size_t)(rbase + arow) * HH + kg;
  f32x4 acc[4];
#pragma unroll
  for (int nt = 0; nt < 4; ++nt) acc[nt] = (f32x4){0.f, 0.f, 0.f, 0.f};
#pragma unroll
  for (int ks = 0; ks < 16; ++ks) {
    bf16x8 a = *(const bf16x8*)(A + ks * 32);
#pragma unroll
    for (int nt = 0; nt < 4; ++nt) {
      const unsigned short* Bp =
          WoutT + (size_t)(nh * 64 + nt * 16 + arow) * HH + kg + ks * 32;
      acc[nt] = __builtin_amdgcn_mfma_f32_16x16x32_bf16(a, *(const bf16x8*)Bp, acc[nt], 0, 0, 0);
    }
  }
#pragma unroll
  for (int nt = 0; nt < 4; ++nt) {
    int n = nh * 64 + nt * 16 + arow;
    float bo = bout[n];
#pragma unroll
    for (int r = 0; r < 4; ++r) {
      int row = rbase + (lane >> 4) * 4 + r;  // t*64 + b
      int t = row >> 6, b = row & 63;
      float v = (acc[nt][r] + bo) * ((wx[b * T_LEN + t] > 0) ? 1.f : 0.f);
      em[(size_t)row * KK + n] = v;
    }
  }
}

// --- 6. CRF forward + gold — E-precompute version ---------------------------
// s_t[k] = em + msc + log( sum_j exp(tl[k][j]) * exp(sc[j]-msc) ).
// E=exp(tl) in LDS (once); p=exp(sc-msc) once per step by 128 threads; inner
// loop is 32 FMA/thread (was 32 expf). msc tracked via wave shuffle-max.
// exp(NEG)=0 exactly; unreachable tags go to -inf (contribute 0 downstream).
__global__ __launch_bounds__(512) void crf_kernel(
    const float* __restrict__ em,             // [256][64][128]
    const float* __restrict__ trans,          // [128][128]
    const int* __restrict__ wx,
    const int* __restrict__ y,                // [64][257]
    float* __restrict__ out) {
  int b = blockIdx.x;
  __shared__ float tl[KK][129];
  __shared__ float El[KK][129];
  __shared__ float sc[KK];
  __shared__ float p[KK];
  __shared__ float red[512];
  __shared__ float red2[512];
  __shared__ float mshare[2];
  int tid = threadIdx.x;
  for (int i = tid; i < KK * KK; i += 512) {
    float v = trans[i];
    tl[i >> 7][i & 127] = v;
    El[i >> 7][i & 127] = __expf(v);          // exp(-1e4) = 0
  }
  if (tid < KK) sc[tid] = (tid == 1) ? 0.f : -10000.f;
  __syncthreads();

  int k = tid & 127, q = tid >> 7, j0 = q * 32;
  float msc = 0.f;                             // max_k sc (k=SOS is 0)

  for (int t = 0; t < T_LEN; ++t) {
    if (wx[b * T_LEN + t] <= 0) continue;      // block-uniform
    if (tid < KK) p[tid] = __expf(sc[tid] - msc);
    __syncthreads();
    float S = 0.f;
#pragma unroll
    for (int j = 0; j < 32; ++j) S += El[k][j0 + j] * p[j0 + j];
    red[tid] = S;
    __syncthreads();
    if (q == 0) {                              // waves 0,1: k = 0..127
      float Sk = S + red[128 + k] + red[256 + k] + red[384 + k];
      float ns = em[(size_t)(t * BB + b) * KK + k] + msc + __logf(Sk);
      sc[k] = ns;
      float m = ns;                            // wave max over 64 lanes
#pragma unroll
      for (int off = 32; off; off >>= 1) m = fmaxf(m, __shfl_xor(m, off));
      if ((tid & 63) == 0) mshare[tid >> 6] = m;
    }
    __syncthreads();
    msc = fmaxf(mshare[0], mshare[1]);
  }

  // gold score
  float term = 0.f, cnt = 0.f;
  if (tid < T_LEN) {
    int yp = y[b * 257 + tid], yn = y[b * 257 + tid + 1];
    if (wx[b * T_LEN + tid] > 0) {
      term = em[(size_t)(tid * BB + b) * KK + yn] + tl[yn][yp];
      cnt = 1.f;
    }
  }
  red[tid] = term; red2[tid] = cnt;
  __syncthreads();
  for (int s2 = 256; s2 > 0; s2 >>= 1) {
    if (tid < s2) { red[tid] += red[tid + s2]; red2[tid] += red2[tid + s2]; }
    __syncthreads();
  }
  float gold = red[0];
  int len = (int)(red2[0] + 0.5f);
  __syncthreads();

  // Z = LSE_k(sc[k] + trans[EOS][k])
  float v = (tid < KK) ? sc[tid] + tl[2][tid] : -3.0e38f;
  red[tid] = v;
  __syncthreads();
  for (int s2 = 256; s2 > 0; s2 >>= 1) {
    if (tid < s2) red[tid] = fmaxf(red[tid], red[tid + s2]);
    __syncthreads();
  }
  float mz = red[0];
  __syncthreads();
  red[tid] = (tid < KK) ? __expf(v - mz) : 0.f;
  __syncthreads();
  for (int s2 = 256; s2 > 0; s2 >>= 1) {
    if (tid < s2) red[tid] += red[tid + s2];
    __syncthreads();
  }
  if (tid == 0) {
    float Z = mz + __logf(red[0]);
    int last_tag = y[b * 257 + len];
    out[b] = Z - (gold + tl[2][last_tag]);
  }
}

// ---------------------------------------------------------------------------
extern "C" void kernel_launch(void* const* d_in, const int* in_sizes, int n_in,
                              void* d_out, int out_size, void* d_ws, size_t ws_size,
                              hipStream_t stream) {
  const int*   cx    = (const int*)d_in[0];
  const int*   wx    = (const int*)d_in[1];
  const int*   y     = (const int*)d_in[2];
  const float* ce    = (const float*)d_in[3];
  const float* we    = (const float*)d_in[4];
  const float* Wi    = (const float*)d_in[5];
  const float* Wh    = (const float*)d_in[6];
  const float* bias  = (const float*)d_in[7];
  const float* Wout  = (const float*)d_in[8];
  const float* bout  = (const float*)d_in[9];
  const float* trans = (const float*)d_in[10];
  float* out = (float*)d_out;

  char* ws = (char*)d_ws;
  // ws layout (16B aligned), ~28.5 MB; em aliases x (x dead after lstm)
  unsigned short* WcatT = (unsigned short*)(ws + 0);          //  3,145,728
  unsigned short* WoutT = (unsigned short*)(ws + 3145728);    //    131,072
  unsigned short* x     = (unsigned short*)(ws + 3276800);    //  8,388,608
  unsigned short* hs    = (unsigned short*)(ws + 11665408);   // 16,777,216
  unsigned int*   flags = (unsigned int*)(ws + 28442624);     //        256
  float*          em    = (float*)(ws + 3276800);             //  8,388,608 (alias x)

  build_wcat<<<384, 256, 0, stream>>>(Wi, Wh, WcatT);
  build_wout<<<16, 256, 0, stream>>>(Wout, WoutT);
  embed_kernel<<<T_LEN * BB, 256, 0, stream>>>(wx, cx, we, ce, x);
  zero_flags<<<1, 64, 0, stream>>>(flags);
  lstm_persistent<<<64, 128, 0, stream>>>(x, hs, WcatT, bias, wx, flags);
  em_gemm<<<256, 512, 0, stream>>>(hs, WoutT, bout, wx, em);
  crf_kernel<<<BB, 512, 0, stream>>>(em, trans, wx, y, out);
}